// Round 1
// baseline (327.577 us; speedup 1.0000x reference)
//
#include <hip/hip_runtime.h>
#include <stdint.h>

typedef __attribute__((ext_vector_type(4))) float f32x4;
typedef __attribute__((ext_vector_type(8))) short bf16x8;
typedef __attribute__((ext_vector_type(2))) unsigned int u32x2;

#define B_SZ   32
#define L_AUD  441000
#define PAD_A  1024
#define LP     443048          // L_AUD + 2*PAD_A
#define T_FR   862
#define J_TOT  27584           // B_SZ * T_FR
#define F_BINS 1025
#define NFFT   2048
#define NB     64
#define FPAD   1152            // 9 * 128
#define NT_J   216             // 27648 / 128
#define NT_F   9
#define ROWB   886096          // LP * 2 bytes per xbp row

#define XBP_OFF   0
#define XBP_BYTES (B_SZ * LP * 2)             // 28,355,072
#define WBT_OFF   XBP_BYTES
#define WBT_BYTES (2 * NT_F * 32 * 16384)     // 9,437,184
#define GB_OFF    (WBT_OFF + WBT_BYTES)
#define GB_BYTES  (NB * FPAD * 2)             // 147,456
#define WS_NEED   (GB_OFF + GB_BYTES)

__device__ __forceinline__ uint16_t f2bf(float f) {
  union { float f; uint32_t u; } c; c.f = f;
  uint32_t r = c.u + 0x7FFFu + ((c.u >> 16) & 1u);
  return (uint16_t)(r >> 16);
}

__device__ __forceinline__ f32x4 mfma16(bf16x8 a, bf16x8 b, f32x4 c) {
  return __builtin_amdgcn_mfma_f32_16x16x32_bf16(a, b, c, 0, 0, 0);
}

// width-16 direct global->LDS; LDS dest is wave-uniform base + lane*16 (linear),
// so swizzling is done on the per-lane GLOBAL source address (m173 pattern).
#define GLD16(g, l) __builtin_amdgcn_global_load_lds( \
    (__attribute__((address_space(1))) void*)(g),     \
    (__attribute__((address_space(3))) void*)(l), 16, 0, 0)

// ---- prep: reflect-padded bf16 audio ------------------------------------
__global__ __launch_bounds__(256) void build_xbp(const float* __restrict__ x,
                                                 uint16_t* __restrict__ xbp) {
  int i = blockIdx.x * 256 + threadIdx.x;     // [32][443048] element
  int b = i / LP;
  int p = i - b * LP;
  int s = p - PAD_A;
  s = s < 0 ? -s : s;
  s = s >= L_AUD ? (2 * L_AUD - 2 - s) : s;
  xbp[i] = f2bf(x[b * L_AUD + s]);
}

// ---- prep: W tiles, bf16, tiled per (plane, f-block, k-step), XOR-swizzled
// byte within 16KB tile = f_local*128 + ((k_local*2) ^ ((f_local&7)<<4))
__global__ __launch_bounds__(256) void build_wbt(const float* __restrict__ wsin,
                                                 const float* __restrict__ wcos,
                                                 char* __restrict__ wbt) {
  int i = blockIdx.x * 256 + threadIdx.x;     // within one plane: 1152*2048
  int sly = blockIdx.y;
  int f = i >> 11;
  int k = i & 2047;
  const float* w = sly ? wcos : wsin;
  float v = (f < F_BINS) ? w[f * NFFT + k] : 0.0f;
  int fbk = f >> 7, fl = f & 127;
  int kk = k >> 6, kl = k & 63;
  size_t tile = ((size_t)sly * NT_F + fbk) * 32 + kk;
  size_t off = tile * 16384 + (size_t)(fl * 128 + ((kl * 2) ^ ((fl & 7) << 4)));
  *(uint16_t*)(wbt + off) = f2bf(v);
}

// ---- prep: gammatone bf16 [64][1152] ------------------------------------
__global__ __launch_bounds__(256) void build_gb(const float* __restrict__ g,
                                                uint16_t* __restrict__ gb) {
  int i = blockIdx.x * 256 + threadIdx.x;     // 64*1152
  int n = i / FPAD;
  int f = i - n * FPAD;
  gb[i] = f2bf(f < F_BINS ? g[n * F_BINS + f] : 0.0f);
}

// ---- main: fused (Wsin,Wcos) x frames -> spec -> G x spec, atomic out ----
__global__ __launch_bounds__(256, 2) void gammatone_main(
    const char* __restrict__ xbp, const char* __restrict__ wbt,
    const char* __restrict__ gb, float* __restrict__ out) {
  __shared__ __align__(16) char smem[49152];
  char* As = smem;            // 16 KB  sin W tile [128f][64k] swizzled
  char* Ac = smem + 16384;    // 16 KB  cos W tile
  char* Bx = smem + 32768;    // 16 KB  frame tile [128j][64k] swizzled

  const int tid = threadIdx.x;
  const int wid = tid >> 6;
  const int lane = tid & 63;
  const int lgrp = lane >> 4;
  const int l15 = lane & 15;
  const int jb = blockIdx.x;
  const int fb = blockIdx.y;
  const int j0 = jb * 128;
  const int f0 = fb * 128;
  const int wr = wid >> 1;    // f half
  const int wc = wid & 1;     // j half

  // B staging: wave wid covers tile rows [wid*32, +32); 4 instrs x (8 rows).
  // lane writes LDS row (i*8 + lane>>3), bytes [(lane&7)*16, +16).
  // source byte inside frame = kk*128 + ((lane&7)*16 ^ ((row&7)<<4)), row&7 == lane>>3.
  const int r8 = lane >> 3;
  const int xorterm = (((lane & 7) ^ r8) << 4);
  size_t fbase[4];
#pragma unroll
  for (int i = 0; i < 4; ++i) {
    int col = j0 + wid * 32 + i * 8 + r8;
    if (col > J_TOT - 1) col = J_TOT - 1;   // padded cols: harmless garbage, never written
    int b = col / T_FR;
    int t = col - b * T_FR;
    fbase[i] = (size_t)b * ROWB + (size_t)t * 1024 + (size_t)xorterm;
  }

  const size_t asbase = (size_t)fb * 32 * 16384;
  const size_t acbase = ((size_t)NT_F + fb) * 32 * 16384;

  f32x4 accS[4][4], accC[4][4];
#pragma unroll
  for (int m = 0; m < 4; ++m)
#pragma unroll
    for (int n = 0; n < 4; ++n) {
      accS[m][n] = (f32x4){0.f, 0.f, 0.f, 0.f};
      accC[m][n] = (f32x4){0.f, 0.f, 0.f, 0.f};
    }

  const int a_row0 = wr * 64 + l15;
  const int b_row0 = wc * 64 + l15;

  for (int kk = 0; kk < 32; ++kk) {
    __syncthreads();   // previous compute done before LDS overwrite
    {
      const char* ga = wbt + asbase + (size_t)kk * 16384 + wid * 4096 + lane * 16;
      const char* gc = wbt + acbase + (size_t)kk * 16384 + wid * 4096 + lane * 16;
      char* la = As + wid * 4096;
      char* lc = Ac + wid * 4096;
      char* lb = Bx + wid * 4096;
#pragma unroll
      for (int i = 0; i < 4; ++i) {
        GLD16(ga + i * 1024, la + i * 1024);
        GLD16(gc + i * 1024, lc + i * 1024);
        GLD16(xbp + fbase[i] + (size_t)kk * 128, lb + i * 1024);
      }
    }
    asm volatile("s_waitcnt vmcnt(0)" ::: "memory");
    __syncthreads();
#pragma unroll
    for (int ks = 0; ks < 2; ++ks) {
      const int kb = ks * 64 + lgrp * 16;
      bf16x8 av[4], cv[4], bv[4];
#pragma unroll
      for (int m = 0; m < 4; ++m) {
        int row = a_row0 + m * 16;
        int off = row * 128 + (kb ^ ((row & 7) << 4));
        av[m] = *(const bf16x8*)(As + off);
        cv[m] = *(const bf16x8*)(Ac + off);
      }
#pragma unroll
      for (int n = 0; n < 4; ++n) {
        int row = b_row0 + n * 16;
        int off = row * 128 + (kb ^ ((row & 7) << 4));
        bv[n] = *(const bf16x8*)(Bx + off);
      }
#pragma unroll
      for (int m = 0; m < 4; ++m)
#pragma unroll
        for (int n = 0; n < 4; ++n) {
          accS[m][n] = mfma16(av[m], bv[n], accS[m][n]);
          accC[m][n] = mfma16(cv[m], bv[n], accC[m][n]);
        }
    }
  }

  __syncthreads();
  // spec = s^2 + c^2 -> LDS as [j 128][f 128] bf16, swizzled:
  // byte = j*256 + ((f*2) ^ ((j&7)<<4)); C/D layout: f=(wr*64+m*16+lgrp*4+r), j=(wc*64+n*16+l15)
#pragma unroll
  for (int m = 0; m < 4; ++m) {
    int frow = wr * 64 + m * 16 + lgrp * 4;
#pragma unroll
    for (int n = 0; n < 4; ++n) {
      int j = wc * 64 + n * 16 + l15;
      f32x4 s = accS[m][n], c = accC[m][n];
      uint32_t lo = (uint32_t)f2bf(s.x * s.x + c.x * c.x) |
                    ((uint32_t)f2bf(s.y * s.y + c.y * c.y) << 16);
      uint32_t hi = (uint32_t)f2bf(s.z * s.z + c.z * c.z) |
                    ((uint32_t)f2bf(s.w * s.w + c.w * c.w) << 16);
      int off = j * 256 + ((frow * 2) ^ ((j & 7) << 4));
      *(u32x2*)(smem + off) = (u32x2){lo, hi};
    }
  }
  __syncthreads();

  // second GEMM: partial_out[64n][128j] = Gb[64][f0:f0+128] x spec[128f][128j]
  // wave wid owns j quarter [wid*32, +32)
  f32x4 acc2[4][2];
#pragma unroll
  for (int m = 0; m < 4; ++m) {
    acc2[m][0] = (f32x4){0.f, 0.f, 0.f, 0.f};
    acc2[m][1] = (f32x4){0.f, 0.f, 0.f, 0.f};
  }
  const int jq = wid * 32;
#pragma unroll
  for (int ks = 0; ks < 4; ++ks) {
    bf16x8 gf[4], sf[2];
#pragma unroll
    for (int m2 = 0; m2 < 4; ++m2) {
      int nrow = m2 * 16 + l15;
      size_t goff = ((size_t)nrow * FPAD + f0 + ks * 32 + lgrp * 8) * 2;
      gf[m2] = *(const bf16x8*)(gb + goff);
    }
#pragma unroll
    for (int nf = 0; nf < 2; ++nf) {
      int j = jq + nf * 16 + l15;
      int off = j * 256 + ((ks * 64 + lgrp * 16) ^ ((j & 7) << 4));
      sf[nf] = *(const bf16x8*)(smem + off);
    }
#pragma unroll
    for (int m2 = 0; m2 < 4; ++m2)
#pragma unroll
      for (int nf = 0; nf < 2; ++nf)
        acc2[m2][nf] = mfma16(gf[m2], sf[nf], acc2[m2][nf]);
  }

#pragma unroll
  for (int nf = 0; nf < 2; ++nf) {
    int jg = j0 + jq + nf * 16 + l15;
    if (jg < J_TOT) {
      int b = jg / T_FR;
      int t = jg - b * T_FR;
      float* ob = out + (size_t)(b * NB) * T_FR + t;
#pragma unroll
      for (int m2 = 0; m2 < 4; ++m2)
#pragma unroll
        for (int r = 0; r < 4; ++r) {
          int nout = m2 * 16 + lgrp * 4 + r;
          atomicAdd(ob + (size_t)nout * T_FR, acc2[m2][nf][r]);
        }
    }
  }
}

extern "C" void kernel_launch(void* const* d_in, const int* in_sizes, int n_in,
                              void* d_out, int out_size, void* d_ws, size_t ws_size,
                              hipStream_t stream) {
  (void)in_sizes; (void)n_in;
  const float* x    = (const float*)d_in[0];
  const float* wsin = (const float*)d_in[1];
  const float* wcos = (const float*)d_in[2];
  const float* g    = (const float*)d_in[3];
  if (ws_size < (size_t)WS_NEED) return;  // need ~38 MB scratch
  char* ws = (char*)d_ws;
  uint16_t* xbp = (uint16_t*)(ws + XBP_OFF);
  char*     wbt = ws + WBT_OFF;
  uint16_t* gbp = (uint16_t*)(ws + GB_OFF);

  hipMemsetAsync(d_out, 0, (size_t)out_size * sizeof(float), stream);
  build_xbp<<<(B_SZ * LP) / 256, 256, 0, stream>>>(x, xbp);
  build_wbt<<<dim3((FPAD * NFFT) / 256, 2), 256, 0, stream>>>(wsin, wcos, wbt);
  build_gb<<<(NB * FPAD) / 256, 256, 0, stream>>>(g, gbp);
  gammatone_main<<<dim3(NT_J, NT_F), 256, 0, stream>>>(
      (const char*)xbp, wbt, (const char*)gbp, (float*)d_out);
}